// Round 1
// baseline (211.360 us; speedup 1.0000x reference)
//
#include <hip/hip_runtime.h>
#include <math.h>

#define BZ   64
#define SEQ  512
#define NBR  16
#define DIM  256
#define NCLS 20

#define SEQ_PER_BLOCK 16   // 4 waves x 4 seq positions each
#define WAVES 4

__global__ __launch_bounds__(256) void zero_ws_kernel(float* __restrict__ ws, int n) {
    int i = blockIdx.x * blockDim.x + threadIdx.x;
    if (i < n) ws[i] = 0.0f;
}

// One wave per (b,s): lane l owns dims [4l, 4l+4). 4 waves/block, 4 seq/wave.
__global__ __launch_bounds__(256) void gnn_gather_kernel(
    const int*   __restrict__ X,        // (BZ, SEQ)
    const int*   __restrict__ NX,       // (BZ, SEQ, NBR)
    const int*   __restrict__ EW,       // (BZ, SEQ, NBR)
    const float* __restrict__ node_emb, // (NUM_NODE, DIM)
    const float* __restrict__ edge_w,   // (EDGE_ROWS, 1)
    const float* __restrict__ node_w,   // (NUM_NODE, 1)
    float*       __restrict__ ypre)     // (BZ, DIM) accumulated
{
    __shared__ float lds[WAVES][DIM];

    const int nchunks = SEQ / SEQ_PER_BLOCK;            // 32
    const int b     = blockIdx.x / nchunks;
    const int chunk = blockIdx.x % nchunks;
    const int wave  = threadIdx.x >> 6;
    const int lane  = threadIdx.x & 63;

    float4 acc = make_float4(0.f, 0.f, 0.f, 0.f);

    #pragma unroll
    for (int i = 0; i < SEQ_PER_BLOCK / WAVES; ++i) {
        const int s  = chunk * SEQ_PER_BLOCK + wave * (SEQ_PER_BLOCK / WAVES) + i;
        const int bs = b * SEQ + s;

        // lanes 0..15 fetch neighbor indices + edge weights
        int   nx = 0;
        float ew = 0.f;
        if (lane < NBR) {
            nx = NX[bs * NBR + lane];
            ew = edge_w[EW[bs * NBR + lane]];
        }

        float4 m = make_float4(-INFINITY, -INFINITY, -INFINITY, -INFINITY);
        #pragma unroll
        for (int k = 0; k < NBR; ++k) {
            const int   n = __shfl(nx, k);
            const float w = __shfl(ew, k);
            const float4 e = *(const float4*)(node_emb + (size_t)n * DIM + 4 * lane);
            m.x = fmaxf(m.x, e.x * w);
            m.y = fmaxf(m.y, e.y * w);
            m.z = fmaxf(m.z, e.z * w);
            m.w = fmaxf(m.w, e.w * w);
        }

        const int   x  = X[bs];
        const float nn = node_w[x];
        const float om = 1.0f - nn;
        const float4 r = *(const float4*)(node_emb + (size_t)x * DIM + 4 * lane);

        acc.x += om * m.x + nn * r.x;
        acc.y += om * m.y + nn * r.y;
        acc.z += om * m.z + nn * r.z;
        acc.w += om * m.w + nn * r.w;
    }

    // block reduce: each wave covers the full 256-dim vector
    *(float4*)&lds[wave][4 * lane] = acc;
    __syncthreads();

    const int t = threadIdx.x;   // 0..255 -> one dim each
    const float sum = lds[0][t] + lds[1][t] + lds[2][t] + lds[3][t];
    atomicAdd(&ypre[b * DIM + t], sum);
}

// One block (64 threads) per batch row: GEMV(256->20) + bias + relu + log_softmax
__global__ __launch_bounds__(64) void gnn_head_kernel(
    const float* __restrict__ ypre,  // (BZ, DIM)
    const float* __restrict__ fc_W,  // (NCLS, DIM)
    const float* __restrict__ fc_b,  // (NCLS,)
    float*       __restrict__ out)   // (BZ, NCLS)
{
    __shared__ float yrow[DIM];
    __shared__ float vals[NCLS];
    __shared__ float lse;

    const int b = blockIdx.x;
    const int t = threadIdx.x;

    ((float4*)yrow)[t] = ((const float4*)(ypre + b * DIM))[t];
    __syncthreads();

    if (t < NCLS) {
        float a = fc_b[t];
        const float* w = fc_W + t * DIM;
        #pragma unroll 4
        for (int d = 0; d < DIM; ++d) a += yrow[d] * w[d];
        vals[t] = fmaxf(a, 0.0f);
    }
    __syncthreads();

    if (t == 0) {
        float mx = -INFINITY;
        for (int c = 0; c < NCLS; ++c) mx = fmaxf(mx, vals[c]);
        float s = 0.0f;
        for (int c = 0; c < NCLS; ++c) s += expf(vals[c] - mx);
        lse = mx + logf(s);
    }
    __syncthreads();

    if (t < NCLS) out[b * NCLS + t] = vals[t] - lse;
}

extern "C" void kernel_launch(void* const* d_in, const int* in_sizes, int n_in,
                              void* d_out, int out_size, void* d_ws, size_t ws_size,
                              hipStream_t stream) {
    const int*   X        = (const int*)  d_in[0];
    const int*   NX       = (const int*)  d_in[1];
    const int*   EW       = (const int*)  d_in[2];
    const float* node_emb = (const float*)d_in[3];
    const float* edge_w   = (const float*)d_in[4];
    const float* node_w   = (const float*)d_in[5];
    const float* fc_W     = (const float*)d_in[6];
    const float* fc_b     = (const float*)d_in[7];
    float* out  = (float*)d_out;
    float* ypre = (float*)d_ws;   // BZ*DIM fp32 accumulator

    zero_ws_kernel<<<(BZ * DIM + 255) / 256, 256, 0, stream>>>(ypre, BZ * DIM);

    gnn_gather_kernel<<<BZ * (SEQ / SEQ_PER_BLOCK), 256, 0, stream>>>(
        X, NX, EW, node_emb, edge_w, node_w, ypre);

    gnn_head_kernel<<<BZ, 64, 0, stream>>>(ypre, fc_W, fc_b, out);
}

// Round 2
// 192.414 us; speedup vs baseline: 1.0985x; 1.0985x over previous
//
#include <hip/hip_runtime.h>
#include <math.h>

#define BZ   64
#define SEQ  512
#define NBR  16
#define DIM  256
#define NCLS 20

#define SEQ_PER_BLOCK 16            // 4 waves x 4 seq positions each
#define NCHUNK (SEQ / SEQ_PER_BLOCK) // 32 blocks per batch row

__device__ __forceinline__ int bcast_i(int v, int lane) {
    return __builtin_amdgcn_readlane(v, lane);   // uniform (SGPR) result
}
__device__ __forceinline__ float bcast_f(float v, int lane) {
    return __int_as_float(__builtin_amdgcn_readlane(__float_as_int(v), lane));
}

__global__ __launch_bounds__(256) void zero_ws_kernel(float* __restrict__ ws, int n) {
    int i = blockIdx.x * blockDim.x + threadIdx.x;
    if (i < n) ws[i] = 0.0f;
}

// One wave per 4 consecutive seq positions. lane l owns dims [4l,4l+4).
// Index/edge loads are done 64-wide (4 pos x 16 nbr == 64 lanes), then
// broadcast via readlane so neighbor ids / weights live in SGPRs and the
// embedding loads use scalar-base addressing (low VGPR pressure).
__global__ __launch_bounds__(256, 4) void gnn_gather_kernel(
    const int*   __restrict__ X,        // (BZ, SEQ)
    const int*   __restrict__ NX,       // (BZ, SEQ, NBR)
    const int*   __restrict__ EW,       // (BZ, SEQ, NBR)
    const float* __restrict__ node_emb, // (NUM_NODE, DIM)
    const float* __restrict__ edge_w,   // (EDGE_ROWS, 1)
    const float* __restrict__ node_w,   // (NUM_NODE, 1)
    float*       __restrict__ dst,      // partials (BZ,NCHUNK,DIM) or atomic (BZ,DIM)
    int use_atomic)
{
    __shared__ float lds[4][DIM];

    const int b     = blockIdx.x / NCHUNK;
    const int chunk = blockIdx.x % NCHUNK;
    const int wave  = threadIdx.x >> 6;
    const int lane  = threadIdx.x & 63;

    const int s0  = chunk * SEQ_PER_BLOCK + wave * 4;
    const int bs0 = b * SEQ + s0;

    // 64-wide coalesced index loads covering this wave's 4 positions.
    // Streams are touched once -> nontemporal to keep node_emb hot in L2.
    const int   nx  = __builtin_nontemporal_load(&NX[bs0 * NBR + lane]);
    const int   ewi = __builtin_nontemporal_load(&EW[bs0 * NBR + lane]);
    const float ew  = __builtin_nontemporal_load(&edge_w[ewi]);

    int   xv  = 0;
    float nwv = 0.f;
    if (lane < 4) {
        xv  = X[bs0 + lane];
        nwv = node_w[xv];
    }

    float4 acc = make_float4(0.f, 0.f, 0.f, 0.f);

    #pragma unroll
    for (int p = 0; p < 4; ++p) {
        float4 m = make_float4(-INFINITY, -INFINITY, -INFINITY, -INFINITY);
        #pragma unroll
        for (int k = 0; k < NBR; ++k) {
            const int   n = bcast_i(nx, p * 16 + k);   // SGPR
            const float w = bcast_f(ew, p * 16 + k);   // SGPR
            const float4 e = *(const float4*)(node_emb + (size_t)n * DIM + 4 * lane);
            m.x = fmaxf(m.x, e.x * w);
            m.y = fmaxf(m.y, e.y * w);
            m.z = fmaxf(m.z, e.z * w);
            m.w = fmaxf(m.w, e.w * w);
        }
        const int   x  = bcast_i(xv, p);
        const float nn = bcast_f(nwv, p);
        const float om = 1.0f - nn;
        const float4 r = *(const float4*)(node_emb + (size_t)x * DIM + 4 * lane);
        acc.x += om * m.x + nn * r.x;
        acc.y += om * m.y + nn * r.y;
        acc.z += om * m.z + nn * r.z;
        acc.w += om * m.w + nn * r.w;
    }

    *(float4*)&lds[wave][4 * lane] = acc;
    __syncthreads();

    const int t = threadIdx.x;   // 0..255 -> one dim each
    const float sum = lds[0][t] + lds[1][t] + lds[2][t] + lds[3][t];
    if (use_atomic) {
        atomicAdd(&dst[b * DIM + t], sum);
    } else {
        dst[(b * NCHUNK + chunk) * DIM + t] = sum;   // private slot, no atomics
    }
}

// One block (256 threads) per batch row: sum partials, GEMV(256->20),
// bias + relu + log_softmax.
__global__ __launch_bounds__(256) void gnn_head_kernel(
    const float* __restrict__ part,  // (BZ, nslots, DIM)
    const float* __restrict__ fc_W,  // (NCLS, DIM)
    const float* __restrict__ fc_b,  // (NCLS,)
    float*       __restrict__ out,   // (BZ, NCLS)
    int nslots)
{
    __shared__ float yrow[DIM];
    __shared__ float vals[NCLS];
    __shared__ float lse;

    const int b = blockIdx.x;
    const int t = threadIdx.x;

    float sum = 0.f;
    for (int c = 0; c < nslots; ++c)
        sum += part[((size_t)b * nslots + c) * DIM + t];
    yrow[t] = sum;
    __syncthreads();

    const int wave = t >> 6;
    const int lane = t & 63;
    const float4 y4 = *(const float4*)&yrow[4 * lane];

    #pragma unroll
    for (int ci = 0; ci < 5; ++ci) {
        const int c = wave * 5 + ci;           // 4 waves x 5 classes = 20
        const float4 w4 = *(const float4*)(fc_W + c * DIM + 4 * lane);
        float d = y4.x * w4.x + y4.y * w4.y + y4.z * w4.z + y4.w * w4.w;
        #pragma unroll
        for (int off = 32; off; off >>= 1) d += __shfl_xor(d, off);
        if (lane == 0) vals[c] = fmaxf(d + fc_b[c], 0.0f);
    }
    __syncthreads();

    if (t == 0) {
        float mx = -INFINITY;
        for (int c = 0; c < NCLS; ++c) mx = fmaxf(mx, vals[c]);
        float s = 0.0f;
        for (int c = 0; c < NCLS; ++c) s += expf(vals[c] - mx);
        lse = mx + logf(s);
    }
    __syncthreads();

    if (t < NCLS) out[b * NCLS + t] = vals[t] - lse;
}

extern "C" void kernel_launch(void* const* d_in, const int* in_sizes, int n_in,
                              void* d_out, int out_size, void* d_ws, size_t ws_size,
                              hipStream_t stream) {
    const int*   X        = (const int*)  d_in[0];
    const int*   NX       = (const int*)  d_in[1];
    const int*   EW       = (const int*)  d_in[2];
    const float* node_emb = (const float*)d_in[3];
    const float* edge_w   = (const float*)d_in[4];
    const float* node_w   = (const float*)d_in[5];
    const float* fc_W     = (const float*)d_in[6];
    const float* fc_b     = (const float*)d_in[7];
    float* out = (float*)d_out;
    float* ws  = (float*)d_ws;

    const size_t need = (size_t)BZ * NCHUNK * DIM * sizeof(float);  // 2 MB
    const int use_atomic = (ws_size < need) ? 1 : 0;

    if (use_atomic) {
        zero_ws_kernel<<<(BZ * DIM + 255) / 256, 256, 0, stream>>>(ws, BZ * DIM);
        gnn_gather_kernel<<<BZ * NCHUNK, 256, 0, stream>>>(
            X, NX, EW, node_emb, edge_w, node_w, ws, 1);
        gnn_head_kernel<<<BZ, 256, 0, stream>>>(ws, fc_W, fc_b, out, 1);
    } else {
        gnn_gather_kernel<<<BZ * NCHUNK, 256, 0, stream>>>(
            X, NX, EW, node_emb, edge_w, node_w, ws, 0);
        gnn_head_kernel<<<BZ, 256, 0, stream>>>(ws, fc_W, fc_b, out, NCHUNK);
    }
}

// Round 3
// 184.546 us; speedup vs baseline: 1.1453x; 1.0426x over previous
//
#include <hip/hip_runtime.h>
#include <math.h>

#define NUM_NODE 5000
#define BZ   64
#define SEQ  512
#define NBR  16
#define DIM  256
#define NCLS 20

#define SEQ_PER_BLOCK 16             // 4 waves x 4 seq positions each
#define NCHUNK (SEQ / SEQ_PER_BLOCK) // 32 blocks per batch row
#define ROWDW (DIM / 2)              // bf16 row stride in dwords (128)

__device__ __forceinline__ int bcast_i(int v, int lane) {
    return __builtin_amdgcn_readlane(v, lane);   // uniform (SGPR) result
}
__device__ __forceinline__ float bcast_f(float v, int lane) {
    return __int_as_float(__builtin_amdgcn_readlane(__float_as_int(v), lane));
}
__device__ __forceinline__ unsigned bf16_rne(float f) {
    unsigned u = __float_as_uint(f);
    return (u + 0x7fffu + ((u >> 16) & 1u)) >> 16;
}

__global__ __launch_bounds__(256) void zero_ws_kernel(float* __restrict__ ws, int n) {
    int i = blockIdx.x * blockDim.x + threadIdx.x;
    if (i < n) ws[i] = 0.0f;
}

// fp32 (NUM_NODE,DIM) -> packed bf16 table (2 dims per dword)
__global__ __launch_bounds__(256) void cvt_emb_kernel(
    const float4* __restrict__ src, uint2* __restrict__ dst, int n4) {
    int i = blockIdx.x * blockDim.x + threadIdx.x;
    if (i < n4) {
        float4 v = src[i];
        uint2 o;
        o.x = bf16_rne(v.x) | (bf16_rne(v.y) << 16);
        o.y = bf16_rne(v.z) | (bf16_rne(v.w) << 16);
        dst[i] = o;
    }
}

// One wave per 4 consecutive seq positions; lane l owns dims [4l,4l+4).
// Neighbor embeddings read from the bf16 L2-resident table (512B/wave-load);
// indices/weights broadcast via readlane -> SGPR scalar addressing.
__global__ __launch_bounds__(256, 8) void gnn_gather_kernel(
    const int*      __restrict__ X,        // (BZ, SEQ)
    const int*      __restrict__ NX,       // (BZ, SEQ, NBR)
    const int*      __restrict__ EW,       // (BZ, SEQ, NBR)
    const float*    __restrict__ node_emb, // (NUM_NODE, DIM) fp32
    const unsigned* __restrict__ emb16,    // (NUM_NODE, ROWDW) packed bf16
    const float*    __restrict__ edge_w,   // (EDGE_ROWS, 1)
    const float*    __restrict__ node_w,   // (NUM_NODE, 1)
    float*          __restrict__ dst,      // partials (BZ,NCHUNK,DIM) or atomic (BZ,DIM)
    int use_atomic)
{
    __shared__ float lds[4][DIM];

    const int b     = blockIdx.x / NCHUNK;
    const int chunk = blockIdx.x % NCHUNK;
    const int wave  = threadIdx.x >> 6;
    const int lane  = threadIdx.x & 63;

    const int s0  = chunk * SEQ_PER_BLOCK + wave * 4;
    const int bs0 = b * SEQ + s0;

    // 64-wide coalesced index loads covering this wave's 4 positions.
    const int   nx  = __builtin_nontemporal_load(&NX[bs0 * NBR + lane]);
    const int   ewi = __builtin_nontemporal_load(&EW[bs0 * NBR + lane]);
    const float ew  = __builtin_nontemporal_load(&edge_w[ewi]);

    int   xv  = 0;
    float nwv = 0.f;
    if (lane < 4) {
        xv  = X[bs0 + lane];
        nwv = node_w[xv];
    }

    float4 acc = make_float4(0.f, 0.f, 0.f, 0.f);

    #pragma unroll
    for (int p = 0; p < 4; ++p) {
        float4 m = make_float4(-INFINITY, -INFINITY, -INFINITY, -INFINITY);
        #pragma unroll
        for (int k = 0; k < NBR; ++k) {
            const int   n = bcast_i(nx, p * 16 + k);   // SGPR
            const float w = bcast_f(ew, p * 16 + k);   // SGPR
            const uint2 e = *(const uint2*)(emb16 + (size_t)n * ROWDW + 2 * lane);
            m.x = fmaxf(m.x, __uint_as_float(e.x << 16)          * w);
            m.y = fmaxf(m.y, __uint_as_float(e.x & 0xffff0000u)  * w);
            m.z = fmaxf(m.z, __uint_as_float(e.y << 16)          * w);
            m.w = fmaxf(m.w, __uint_as_float(e.y & 0xffff0000u)  * w);
        }
        const int   x  = bcast_i(xv, p);
        const float nn = bcast_f(nwv, p);
        const float om = 1.0f - nn;
        const float4 r = *(const float4*)(node_emb + (size_t)x * DIM + 4 * lane); // fp32 self-term
        acc.x += om * m.x + nn * r.x;
        acc.y += om * m.y + nn * r.y;
        acc.z += om * m.z + nn * r.z;
        acc.w += om * m.w + nn * r.w;
    }

    *(float4*)&lds[wave][4 * lane] = acc;
    __syncthreads();

    const int t = threadIdx.x;   // 0..255 -> one dim each
    const float sum = lds[0][t] + lds[1][t] + lds[2][t] + lds[3][t];
    if (use_atomic) {
        atomicAdd(&dst[b * DIM + t], sum);
    } else {
        dst[(b * NCHUNK + chunk) * DIM + t] = sum;   // private slot, no atomics
    }
}

// One block (256 threads) per batch row: sum partials, GEMV(256->20),
// bias + relu + log_softmax.
__global__ __launch_bounds__(256) void gnn_head_kernel(
    const float* __restrict__ part,  // (BZ, nslots, DIM)
    const float* __restrict__ fc_W,  // (NCLS, DIM)
    const float* __restrict__ fc_b,  // (NCLS,)
    float*       __restrict__ out,   // (BZ, NCLS)
    int nslots)
{
    __shared__ float yrow[DIM];
    __shared__ float vals[NCLS];
    __shared__ float lse;

    const int b = blockIdx.x;
    const int t = threadIdx.x;

    float sum = 0.f;
    for (int c = 0; c < nslots; ++c)
        sum += part[((size_t)b * nslots + c) * DIM + t];
    yrow[t] = sum;
    __syncthreads();

    const int wave = t >> 6;
    const int lane = t & 63;
    const float4 y4 = *(const float4*)&yrow[4 * lane];

    #pragma unroll
    for (int ci = 0; ci < 5; ++ci) {
        const int c = wave * 5 + ci;           // 4 waves x 5 classes = 20
        const float4 w4 = *(const float4*)(fc_W + c * DIM + 4 * lane);
        float d = y4.x * w4.x + y4.y * w4.y + y4.z * w4.z + y4.w * w4.w;
        #pragma unroll
        for (int off = 32; off; off >>= 1) d += __shfl_xor(d, off);
        if (lane == 0) vals[c] = fmaxf(d + fc_b[c], 0.0f);
    }
    __syncthreads();

    if (t == 0) {
        float mx = -INFINITY;
        for (int c = 0; c < NCLS; ++c) mx = fmaxf(mx, vals[c]);
        float s = 0.0f;
        for (int c = 0; c < NCLS; ++c) s += expf(vals[c] - mx);
        lse = mx + logf(s);
    }
    __syncthreads();

    if (t < NCLS) out[b * NCLS + t] = vals[t] - lse;
}

extern "C" void kernel_launch(void* const* d_in, const int* in_sizes, int n_in,
                              void* d_out, int out_size, void* d_ws, size_t ws_size,
                              hipStream_t stream) {
    const int*   X        = (const int*)  d_in[0];
    const int*   NX       = (const int*)  d_in[1];
    const int*   EW       = (const int*)  d_in[2];
    const float* node_emb = (const float*)d_in[3];
    const float* edge_w   = (const float*)d_in[4];
    const float* node_w   = (const float*)d_in[5];
    const float* fc_W     = (const float*)d_in[6];
    const float* fc_b     = (const float*)d_in[7];
    float* out = (float*)d_out;

    const size_t part_bytes = (size_t)BZ * NCHUNK * DIM * sizeof(float);      // 2 MB
    const size_t emb_bytes  = (size_t)NUM_NODE * DIM * sizeof(unsigned short); // 2.56 MB
    float*    part  = (float*)d_ws;
    unsigned* emb16 = (unsigned*)((char*)d_ws + part_bytes);

    if (ws_size >= part_bytes + emb_bytes) {
        const int n4 = NUM_NODE * DIM / 4;   // 320000
        cvt_emb_kernel<<<(n4 + 255) / 256, 256, 0, stream>>>(
            (const float4*)node_emb, (uint2*)emb16, n4);
        gnn_gather_kernel<<<BZ * NCHUNK, 256, 0, stream>>>(
            X, NX, EW, node_emb, emb16, edge_w, node_w, part, 0);
        gnn_head_kernel<<<BZ, 256, 0, stream>>>(part, fc_W, fc_b, out, NCHUNK);
    } else {
        // fallback: fp32 gathers with atomic accumulation (needs only 64 KB)
        zero_ws_kernel<<<(BZ * DIM + 255) / 256, 256, 0, stream>>>(part, BZ * DIM);
        // reuse gather with emb16 pointing at a dummy; instead run bf16-free path:
        // build a tiny bf16 table is impossible -> use fp32 table via emb16==nullptr
        // Simplest: still convert if at least emb_bytes fit after 32KB partials.
        gnn_gather_kernel<<<BZ * NCHUNK, 256, 0, stream>>>(
            X, NX, EW, node_emb, (const unsigned*)node_emb, edge_w, node_w, part, 1);
        gnn_head_kernel<<<BZ, 256, 0, stream>>>(part, fc_W, fc_b, out, 1);
    }
}

// Round 4
// 183.228 us; speedup vs baseline: 1.1535x; 1.0072x over previous
//
#include <hip/hip_runtime.h>
#include <math.h>

#define NUM_NODE 5000
#define BZ   64
#define SEQ  512
#define NBR  16
#define DIM  256
#define NCLS 20

#define SEQ_PER_BLOCK 16             // 4 waves x 4 seq positions each
#define NCHUNK (SEQ / SEQ_PER_BLOCK) // 32 blocks per batch row
#define ROWB  (DIM * 2)              // bf16 row bytes (512)

__device__ __forceinline__ int bcast_i(int v, int lane) {
    return __builtin_amdgcn_readlane(v, lane);   // uniform (SGPR) result
}
__device__ __forceinline__ float bcast_f(float v, int lane) {
    return __int_as_float(__builtin_amdgcn_readlane(__float_as_int(v), lane));
}
__device__ __forceinline__ unsigned bf16_rne(float f) {
    unsigned u = __float_as_uint(f);
    return (u + 0x7fffu + ((u >> 16) & 1u)) >> 16;
}
__device__ __forceinline__ float lo_bf16(unsigned u) { return __uint_as_float(u << 16); }
__device__ __forceinline__ float hi_bf16(unsigned u) { return __uint_as_float(u & 0xffff0000u); }

__global__ __launch_bounds__(256) void zero_ws_kernel(float* __restrict__ ws, int n) {
    int i = blockIdx.x * blockDim.x + threadIdx.x;
    if (i < n) ws[i] = 0.0f;
}

// fp32 (NUM_NODE,DIM) -> packed bf16 table (2 dims per dword)
__global__ __launch_bounds__(256) void cvt_emb_kernel(
    const float4* __restrict__ src, uint2* __restrict__ dst, int n4) {
    int i = blockIdx.x * blockDim.x + threadIdx.x;
    if (i < n4) {
        float4 v = src[i];
        uint2 o;
        o.x = bf16_rne(v.x) | (bf16_rne(v.y) << 16);
        o.y = bf16_rne(v.z) | (bf16_rne(v.w) << 16);
        dst[i] = o;
    }
}

// One wave per 4 consecutive seq positions. Gather loads are uint4 (16B/lane):
// 32 lanes cover one 512B bf16 row, so each load instruction fetches TWO
// neighbor rows (lanes 0-31 -> neighbor 2j, lanes 32-63 -> neighbor 2j+1).
// Halves are max-combined with one shfl_xor(32). 36 VMEM instrs/wave vs 68.
__global__ __launch_bounds__(256, 4) void gnn_gather_kernel(
    const int*   __restrict__ X,        // (BZ, SEQ)
    const int*   __restrict__ NX,       // (BZ, SEQ, NBR)
    const int*   __restrict__ EW,       // (BZ, SEQ, NBR)
    const float* __restrict__ node_emb, // (NUM_NODE, DIM) fp32
    const char*  __restrict__ embb,     // (NUM_NODE, ROWB) packed bf16 table
    const float* __restrict__ edge_w,   // (EDGE_ROWS, 1)
    const float* __restrict__ node_w,   // (NUM_NODE, 1)
    float*       __restrict__ dst)      // partials (BZ, NCHUNK, DIM)
{
    __shared__ float lds[4][DIM];

    const int b     = blockIdx.x / NCHUNK;
    const int chunk = blockIdx.x % NCHUNK;
    const int wave  = threadIdx.x >> 6;
    const int lane  = threadIdx.x & 63;
    const int half  = lane >> 5;
    const int sub   = lane & 31;
    const int voff  = sub * 16;          // byte offset within a bf16 row

    const int s0  = chunk * SEQ_PER_BLOCK + wave * 4;
    const int bs0 = b * SEQ + s0;

    // 64-wide coalesced index loads covering this wave's 4 positions.
    const int   nx  = __builtin_nontemporal_load(&NX[bs0 * NBR + lane]);
    const int   ewi = __builtin_nontemporal_load(&EW[bs0 * NBR + lane]);
    const float ew  = __builtin_nontemporal_load(&edge_w[ewi]);

    int   xv  = 0;
    float nwv = 0.f;
    if (lane < 4) {
        xv  = X[bs0 + lane];
        nwv = node_w[xv];
    }

    float acc[8] = {0.f, 0.f, 0.f, 0.f, 0.f, 0.f, 0.f, 0.f};

    #pragma unroll
    for (int p = 0; p < 4; ++p) {
        float m[8];
        #pragma unroll
        for (int i = 0; i < 8; ++i) m[i] = -INFINITY;

        #pragma unroll
        for (int j = 0; j < 8; ++j) {              // 2 neighbors per iteration
            const int   n0 = bcast_i(nx, p * 16 + 2 * j);
            const int   n1 = bcast_i(nx, p * 16 + 2 * j + 1);
            const float w0 = bcast_f(ew, p * 16 + 2 * j);
            const float w1 = bcast_f(ew, p * 16 + 2 * j + 1);
            const int   n  = half ? n1 : n0;
            const float w  = half ? w1 : w0;
            const uint4 e  = *(const uint4*)(embb + ((size_t)n * ROWB) + voff);
            m[0] = fmaxf(m[0], lo_bf16(e.x) * w);
            m[1] = fmaxf(m[1], hi_bf16(e.x) * w);
            m[2] = fmaxf(m[2], lo_bf16(e.y) * w);
            m[3] = fmaxf(m[3], hi_bf16(e.y) * w);
            m[4] = fmaxf(m[4], lo_bf16(e.z) * w);
            m[5] = fmaxf(m[5], hi_bf16(e.z) * w);
            m[6] = fmaxf(m[6], lo_bf16(e.w) * w);
            m[7] = fmaxf(m[7], hi_bf16(e.w) * w);
        }

        // combine the two half-wave neighbor subsets
        #pragma unroll
        for (int i = 0; i < 8; ++i)
            m[i] = fmaxf(m[i], __shfl_xor(m[i], 32));

        const int   x  = bcast_i(xv, p);
        const float nn = bcast_f(nwv, p);
        const float om = 1.0f - nn;
        // self row (fp32) in the same 8-dims-per-lane layout (halves duplicate)
        const float4 ra = *(const float4*)(node_emb + (size_t)x * DIM + 8 * sub);
        const float4 rb = *(const float4*)(node_emb + (size_t)x * DIM + 8 * sub + 4);
        acc[0] += om * m[0] + nn * ra.x;
        acc[1] += om * m[1] + nn * ra.y;
        acc[2] += om * m[2] + nn * ra.z;
        acc[3] += om * m[3] + nn * ra.w;
        acc[4] += om * m[4] + nn * rb.x;
        acc[5] += om * m[5] + nn * rb.y;
        acc[6] += om * m[6] + nn * rb.z;
        acc[7] += om * m[7] + nn * rb.w;
    }

    if (half == 0) {
        *(float4*)&lds[wave][8 * sub]     = make_float4(acc[0], acc[1], acc[2], acc[3]);
        *(float4*)&lds[wave][8 * sub + 4] = make_float4(acc[4], acc[5], acc[6], acc[7]);
    }
    __syncthreads();

    const int t = threadIdx.x;   // 0..255 -> one dim each
    dst[((size_t)b * NCHUNK + chunk) * DIM + t] =
        lds[0][t] + lds[1][t] + lds[2][t] + lds[3][t];
}

// Fallback (tiny ws): fp32 gathers, atomic accumulation into (BZ,DIM).
__global__ __launch_bounds__(256) void gnn_gather_f32_kernel(
    const int*   __restrict__ X,
    const int*   __restrict__ NX,
    const int*   __restrict__ EW,
    const float* __restrict__ node_emb,
    const float* __restrict__ edge_w,
    const float* __restrict__ node_w,
    float*       __restrict__ dst)      // (BZ, DIM) atomic
{
    __shared__ float lds[4][DIM];
    const int b     = blockIdx.x / NCHUNK;
    const int chunk = blockIdx.x % NCHUNK;
    const int wave  = threadIdx.x >> 6;
    const int lane  = threadIdx.x & 63;
    const int s0  = chunk * SEQ_PER_BLOCK + wave * 4;
    const int bs0 = b * SEQ + s0;

    const int   nx  = NX[bs0 * NBR + lane];
    const float ew  = edge_w[EW[bs0 * NBR + lane]];
    int xv = 0; float nwv = 0.f;
    if (lane < 4) { xv = X[bs0 + lane]; nwv = node_w[xv]; }

    float4 acc = make_float4(0.f, 0.f, 0.f, 0.f);
    for (int p = 0; p < 4; ++p) {
        float4 m = make_float4(-INFINITY, -INFINITY, -INFINITY, -INFINITY);
        for (int k = 0; k < NBR; ++k) {
            const int   n = bcast_i(nx, p * 16 + k);
            const float w = bcast_f(ew, p * 16 + k);
            const float4 e = *(const float4*)(node_emb + (size_t)n * DIM + 4 * lane);
            m.x = fmaxf(m.x, e.x * w); m.y = fmaxf(m.y, e.y * w);
            m.z = fmaxf(m.z, e.z * w); m.w = fmaxf(m.w, e.w * w);
        }
        const int   x  = bcast_i(xv, p);
        const float nn = bcast_f(nwv, p);
        const float om = 1.0f - nn;
        const float4 r = *(const float4*)(node_emb + (size_t)x * DIM + 4 * lane);
        acc.x += om * m.x + nn * r.x; acc.y += om * m.y + nn * r.y;
        acc.z += om * m.z + nn * r.z; acc.w += om * m.w + nn * r.w;
    }
    *(float4*)&lds[wave][4 * lane] = acc;
    __syncthreads();
    const int t = threadIdx.x;
    atomicAdd(&dst[b * DIM + t], lds[0][t] + lds[1][t] + lds[2][t] + lds[3][t]);
}

// One block (256 threads) per batch row: sum partials, GEMV(256->20),
// bias + relu + log_softmax.
__global__ __launch_bounds__(256) void gnn_head_kernel(
    const float* __restrict__ part,  // (BZ, nslots, DIM)
    const float* __restrict__ fc_W,  // (NCLS, DIM)
    const float* __restrict__ fc_b,  // (NCLS,)
    float*       __restrict__ out,   // (BZ, NCLS)
    int nslots)
{
    __shared__ float yrow[DIM];
    __shared__ float vals[NCLS];
    __shared__ float lse;

    const int b = blockIdx.x;
    const int t = threadIdx.x;

    float sum = 0.f;
    for (int c = 0; c < nslots; ++c)
        sum += part[((size_t)b * nslots + c) * DIM + t];
    yrow[t] = sum;
    __syncthreads();

    const int wave = t >> 6;
    const int lane = t & 63;
    const float4 y4 = *(const float4*)&yrow[4 * lane];

    #pragma unroll
    for (int ci = 0; ci < 5; ++ci) {
        const int c = wave * 5 + ci;           // 4 waves x 5 classes = 20
        const float4 w4 = *(const float4*)(fc_W + c * DIM + 4 * lane);
        float d = y4.x * w4.x + y4.y * w4.y + y4.z * w4.z + y4.w * w4.w;
        #pragma unroll
        for (int off = 32; off; off >>= 1) d += __shfl_xor(d, off);
        if (lane == 0) vals[c] = fmaxf(d + fc_b[c], 0.0f);
    }
    __syncthreads();

    if (t == 0) {
        float mx = -INFINITY;
        for (int c = 0; c < NCLS; ++c) mx = fmaxf(mx, vals[c]);
        float s = 0.0f;
        for (int c = 0; c < NCLS; ++c) s += expf(vals[c] - mx);
        lse = mx + logf(s);
    }
    __syncthreads();

    if (t < NCLS) out[b * NCLS + t] = vals[t] - lse;
}

extern "C" void kernel_launch(void* const* d_in, const int* in_sizes, int n_in,
                              void* d_out, int out_size, void* d_ws, size_t ws_size,
                              hipStream_t stream) {
    const int*   X        = (const int*)  d_in[0];
    const int*   NX       = (const int*)  d_in[1];
    const int*   EW       = (const int*)  d_in[2];
    const float* node_emb = (const float*)d_in[3];
    const float* edge_w   = (const float*)d_in[4];
    const float* node_w   = (const float*)d_in[5];
    const float* fc_W     = (const float*)d_in[6];
    const float* fc_b     = (const float*)d_in[7];
    float* out = (float*)d_out;

    const size_t part_bytes = (size_t)BZ * NCHUNK * DIM * sizeof(float);       // 2 MB
    const size_t emb_bytes  = (size_t)NUM_NODE * DIM * sizeof(unsigned short); // 2.56 MB
    float* part = (float*)d_ws;
    char*  embb = (char*)d_ws + part_bytes;

    if (ws_size >= part_bytes + emb_bytes) {
        const int n4 = NUM_NODE * DIM / 4;   // 320000
        cvt_emb_kernel<<<(n4 + 255) / 256, 256, 0, stream>>>(
            (const float4*)node_emb, (uint2*)embb, n4);
        gnn_gather_kernel<<<BZ * NCHUNK, 256, 0, stream>>>(
            X, NX, EW, node_emb, embb, edge_w, node_w, part);
        gnn_head_kernel<<<BZ, 256, 0, stream>>>(part, fc_W, fc_b, out, NCHUNK);
    } else {
        zero_ws_kernel<<<(BZ * DIM + 255) / 256, 256, 0, stream>>>(part, BZ * DIM);
        gnn_gather_f32_kernel<<<BZ * NCHUNK, 256, 0, stream>>>(
            X, NX, EW, node_emb, edge_w, node_w, part);
        gnn_head_kernel<<<BZ, 256, 0, stream>>>(part, fc_W, fc_b, out, 1);
    }
}

// Round 5
// 182.080 us; speedup vs baseline: 1.1608x; 1.0063x over previous
//
#include <hip/hip_runtime.h>
#include <math.h>

#define NUM_NODE 5000
#define BZ   64
#define SEQ  512
#define NBR  16
#define DIM  256
#define NCLS 20

#define ROWB  (DIM * 2)        // bf16 row bytes (512)
#define NCHUNK2 (SEQ / 4)      // 128 blocks per batch row (1 position per wave)
#define NCHUNK16 (SEQ / 16)    // fallback mapping

__device__ __forceinline__ int bcast_i(int v, int lane) {
    return __builtin_amdgcn_readlane(v, lane);   // uniform (SGPR) result
}
__device__ __forceinline__ float bcast_f(float v, int lane) {
    return __int_as_float(__builtin_amdgcn_readlane(__float_as_int(v), lane));
}
__device__ __forceinline__ unsigned bf16_rne(float f) {
    unsigned u = __float_as_uint(f);
    return (u + 0x7fffu + ((u >> 16) & 1u)) >> 16;
}
__device__ __forceinline__ float lo_bf16(unsigned u) { return __uint_as_float(u << 16); }
__device__ __forceinline__ float hi_bf16(unsigned u) { return __uint_as_float(u & 0xffff0000u); }

__global__ __launch_bounds__(256) void zero_ws_kernel(float* __restrict__ ws, int n) {
    int i = blockIdx.x * blockDim.x + threadIdx.x;
    if (i < n) ws[i] = 0.0f;
}

// fp32 (NUM_NODE,DIM) -> packed bf16 table (2 dims per dword)
__global__ __launch_bounds__(256) void cvt_emb_kernel(
    const float4* __restrict__ src, uint2* __restrict__ dst, int n4) {
    int i = blockIdx.x * blockDim.x + threadIdx.x;
    if (i < n4) {
        float4 v = src[i];
        uint2 o;
        o.x = bf16_rne(v.x) | (bf16_rne(v.y) << 16);
        o.y = bf16_rne(v.z) | (bf16_rne(v.w) << 16);
        dst[i] = o;
    }
}

// One wave per (b,s) position. A 16B/lane uint4 load covers TWO 512B bf16
// rows (lanes 0-31 -> neighbor 2j, lanes 32-63 -> neighbor 2j+1), so the
// whole neighborhood is 8 loads. ALL gathers are issued into e[8] BEFORE any
// consumption -> deep in-flight pipeline instead of load->use serialization.
// 32768 waves give the scheduler TLP to hide the rest.
__global__ __launch_bounds__(256, 4) void gnn_gather_kernel(
    const int*   __restrict__ X,        // (BZ, SEQ)
    const int*   __restrict__ NX,       // (BZ, SEQ, NBR)
    const int*   __restrict__ EW,       // (BZ, SEQ, NBR)
    const char*  __restrict__ embb,     // (NUM_NODE, ROWB) packed bf16 table
    const float* __restrict__ edge_w,   // (EDGE_ROWS, 1)
    const float* __restrict__ node_w,   // (NUM_NODE, 1)
    float*       __restrict__ dst)      // partials (BZ, NCHUNK2, DIM)
{
    __shared__ float lds[4][DIM];

    const int b     = blockIdx.x / NCHUNK2;
    const int chunk = blockIdx.x % NCHUNK2;
    const int wave  = threadIdx.x >> 6;
    const int lane  = threadIdx.x & 63;
    const int half  = lane >> 5;
    const int sub   = lane & 31;
    const int voff  = sub * 16;          // byte offset within a bf16 row

    const int s  = chunk * 4 + wave;
    const int bs = b * SEQ + s;

    // 16 lanes fetch this position's neighbor ids / edge-weight indices
    int   nxv = 0;
    float ewv = 0.f;
    if (lane < NBR) {
        nxv = __builtin_nontemporal_load(&NX[bs * NBR + lane]);
        const int ewi = __builtin_nontemporal_load(&EW[bs * NBR + lane]);
        ewv = __builtin_nontemporal_load(&edge_w[ewi]);
    }
    const int   x  = X[bs];        // wave-uniform address -> broadcast line
    const float nn = node_w[x];

    // ---- issue ALL gather loads back-to-back ----
    uint4 e[8];
    #pragma unroll
    for (int j = 0; j < 8; ++j) {
        const int n0 = bcast_i(nxv, 2 * j);
        const int n1 = bcast_i(nxv, 2 * j + 1);
        const int n  = half ? n1 : n0;
        e[j] = *(const uint4*)(embb + (size_t)n * ROWB + voff);
    }
    const uint4 es = *(const uint4*)(embb + (size_t)x * ROWB + voff); // self row

    // ---- consume in issue order (decreasing vmcnt) ----
    float m[8];
    #pragma unroll
    for (int i = 0; i < 8; ++i) m[i] = -INFINITY;

    #pragma unroll
    for (int j = 0; j < 8; ++j) {
        const float w0 = bcast_f(ewv, 2 * j);
        const float w1 = bcast_f(ewv, 2 * j + 1);
        const float w  = half ? w1 : w0;
        m[0] = fmaxf(m[0], lo_bf16(e[j].x) * w);
        m[1] = fmaxf(m[1], hi_bf16(e[j].x) * w);
        m[2] = fmaxf(m[2], lo_bf16(e[j].y) * w);
        m[3] = fmaxf(m[3], hi_bf16(e[j].y) * w);
        m[4] = fmaxf(m[4], lo_bf16(e[j].z) * w);
        m[5] = fmaxf(m[5], hi_bf16(e[j].z) * w);
        m[6] = fmaxf(m[6], lo_bf16(e[j].w) * w);
        m[7] = fmaxf(m[7], hi_bf16(e[j].w) * w);
    }

    // combine the two half-wave neighbor subsets
    #pragma unroll
    for (int i = 0; i < 8; ++i)
        m[i] = fmaxf(m[i], __shfl_xor(m[i], 32));

    const float om = 1.0f - nn;
    float acc[8];
    acc[0] = om * m[0] + nn * lo_bf16(es.x);
    acc[1] = om * m[1] + nn * hi_bf16(es.x);
    acc[2] = om * m[2] + nn * lo_bf16(es.y);
    acc[3] = om * m[3] + nn * hi_bf16(es.y);
    acc[4] = om * m[4] + nn * lo_bf16(es.z);
    acc[5] = om * m[5] + nn * hi_bf16(es.z);
    acc[6] = om * m[6] + nn * lo_bf16(es.w);
    acc[7] = om * m[7] + nn * hi_bf16(es.w);

    if (half == 0) {
        *(float4*)&lds[wave][8 * sub]     = make_float4(acc[0], acc[1], acc[2], acc[3]);
        *(float4*)&lds[wave][8 * sub + 4] = make_float4(acc[4], acc[5], acc[6], acc[7]);
    }
    __syncthreads();

    const int t = threadIdx.x;   // 0..255 -> one dim each
    dst[(size_t)blockIdx.x * DIM + t] =
        lds[0][t] + lds[1][t] + lds[2][t] + lds[3][t];
}

// Fallback (tiny ws): fp32 gathers, atomic accumulation into (BZ,DIM).
__global__ __launch_bounds__(256) void gnn_gather_f32_kernel(
    const int*   __restrict__ X,
    const int*   __restrict__ NX,
    const int*   __restrict__ EW,
    const float* __restrict__ node_emb,
    const float* __restrict__ edge_w,
    const float* __restrict__ node_w,
    float*       __restrict__ dst)      // (BZ, DIM) atomic
{
    __shared__ float lds[4][DIM];
    const int b     = blockIdx.x / NCHUNK16;
    const int chunk = blockIdx.x % NCHUNK16;
    const int wave  = threadIdx.x >> 6;
    const int lane  = threadIdx.x & 63;
    const int s0  = chunk * 16 + wave * 4;
    const int bs0 = b * SEQ + s0;

    const int   nx  = NX[bs0 * NBR + lane];
    const float ew  = edge_w[EW[bs0 * NBR + lane]];
    int xv = 0; float nwv = 0.f;
    if (lane < 4) { xv = X[bs0 + lane]; nwv = node_w[xv]; }

    float4 acc = make_float4(0.f, 0.f, 0.f, 0.f);
    for (int p = 0; p < 4; ++p) {
        float4 m = make_float4(-INFINITY, -INFINITY, -INFINITY, -INFINITY);
        for (int k = 0; k < NBR; ++k) {
            const int   n = bcast_i(nx, p * 16 + k);
            const float w = bcast_f(ew, p * 16 + k);
            const float4 e = *(const float4*)(node_emb + (size_t)n * DIM + 4 * lane);
            m.x = fmaxf(m.x, e.x * w); m.y = fmaxf(m.y, e.y * w);
            m.z = fmaxf(m.z, e.z * w); m.w = fmaxf(m.w, e.w * w);
        }
        const int   x  = bcast_i(xv, p);
        const float nn = bcast_f(nwv, p);
        const float om = 1.0f - nn;
        const float4 r = *(const float4*)(node_emb + (size_t)x * DIM + 4 * lane);
        acc.x += om * m.x + nn * r.x; acc.y += om * m.y + nn * r.y;
        acc.z += om * m.z + nn * r.z; acc.w += om * m.w + nn * r.w;
    }
    *(float4*)&lds[wave][4 * lane] = acc;
    __syncthreads();
    const int t = threadIdx.x;
    atomicAdd(&dst[b * DIM + t], lds[0][t] + lds[1][t] + lds[2][t] + lds[3][t]);
}

// One block (256 threads) per batch row: sum partials, GEMV(256->20),
// bias + relu + log_softmax.
__global__ __launch_bounds__(256) void gnn_head_kernel(
    const float* __restrict__ part,  // (BZ, nslots, DIM)
    const float* __restrict__ fc_W,  // (NCLS, DIM)
    const float* __restrict__ fc_b,  // (NCLS,)
    float*       __restrict__ out,   // (BZ, NCLS)
    int nslots)
{
    __shared__ float yrow[DIM];
    __shared__ float vals[NCLS];
    __shared__ float lse;

    const int b = blockIdx.x;
    const int t = threadIdx.x;

    float sum = 0.f;
    #pragma unroll 4
    for (int c = 0; c < nslots; ++c)
        sum += part[((size_t)b * nslots + c) * DIM + t];
    yrow[t] = sum;
    __syncthreads();

    const int wave = t >> 6;
    const int lane = t & 63;
    const float4 y4 = *(const float4*)&yrow[4 * lane];

    #pragma unroll
    for (int ci = 0; ci < 5; ++ci) {
        const int c = wave * 5 + ci;           // 4 waves x 5 classes = 20
        const float4 w4 = *(const float4*)(fc_W + c * DIM + 4 * lane);
        float d = y4.x * w4.x + y4.y * w4.y + y4.z * w4.z + y4.w * w4.w;
        #pragma unroll
        for (int off = 32; off; off >>= 1) d += __shfl_xor(d, off);
        if (lane == 0) vals[c] = fmaxf(d + fc_b[c], 0.0f);
    }
    __syncthreads();

    if (t == 0) {
        float mx = -INFINITY;
        for (int c = 0; c < NCLS; ++c) mx = fmaxf(mx, vals[c]);
        float s = 0.0f;
        for (int c = 0; c < NCLS; ++c) s += expf(vals[c] - mx);
        lse = mx + logf(s);
    }
    __syncthreads();

    if (t < NCLS) out[b * NCLS + t] = vals[t] - lse;
}

extern "C" void kernel_launch(void* const* d_in, const int* in_sizes, int n_in,
                              void* d_out, int out_size, void* d_ws, size_t ws_size,
                              hipStream_t stream) {
    const int*   X        = (const int*)  d_in[0];
    const int*   NX       = (const int*)  d_in[1];
    const int*   EW       = (const int*)  d_in[2];
    const float* node_emb = (const float*)d_in[3];
    const float* edge_w   = (const float*)d_in[4];
    const float* node_w   = (const float*)d_in[5];
    const float* fc_W     = (const float*)d_in[6];
    const float* fc_b     = (const float*)d_in[7];
    float* out = (float*)d_out;

    const size_t part_bytes = (size_t)BZ * NCHUNK2 * DIM * sizeof(float);      // 8 MB
    const size_t emb_bytes  = (size_t)NUM_NODE * DIM * sizeof(unsigned short); // 2.56 MB
    float* part = (float*)d_ws;
    char*  embb = (char*)d_ws + part_bytes;

    if (ws_size >= part_bytes + emb_bytes) {
        const int n4 = NUM_NODE * DIM / 4;   // 320000
        cvt_emb_kernel<<<(n4 + 255) / 256, 256, 0, stream>>>(
            (const float4*)node_emb, (uint2*)embb, n4);
        gnn_gather_kernel<<<BZ * NCHUNK2, 256, 0, stream>>>(
            X, NX, EW, embb, edge_w, node_w, part);
        gnn_head_kernel<<<BZ, 256, 0, stream>>>(part, fc_W, fc_b, out, NCHUNK2);
    } else {
        zero_ws_kernel<<<(BZ * DIM + 255) / 256, 256, 0, stream>>>(part, BZ * DIM);
        gnn_gather_f32_kernel<<<BZ * NCHUNK16, 256, 0, stream>>>(
            X, NX, EW, node_emb, edge_w, node_w, part);
        gnn_head_kernel<<<BZ, 256, 0, stream>>>(part, fc_W, fc_b, out, 1);
    }
}

// Round 6
// 175.735 us; speedup vs baseline: 1.2027x; 1.0361x over previous
//
#include <hip/hip_runtime.h>
#include <math.h>

#define NUM_NODE 5000
#define BZ   64
#define SEQ  512
#define NBR  16
#define DIM  256
#define NCLS 20

#define ROWB  (DIM * 2)        // bf16 row bytes (512)
#define NCHUNK2 (SEQ / 4)      // 128 blocks per batch row (1 position per wave)
#define NCHUNK16 (SEQ / 16)    // fallback mapping

__device__ __forceinline__ int bcast_i(int v, int lane) {
    return __builtin_amdgcn_readlane(v, lane);   // uniform (SGPR) result
}
__device__ __forceinline__ float bcast_f(float v, int lane) {
    return __int_as_float(__builtin_amdgcn_readlane(__float_as_int(v), lane));
}
__device__ __forceinline__ unsigned bf16_rne(float f) {
    unsigned u = __float_as_uint(f);
    return (u + 0x7fffu + ((u >> 16) & 1u)) >> 16;
}
__device__ __forceinline__ float lo_bf16(unsigned u) { return __uint_as_float(u << 16); }
__device__ __forceinline__ float hi_bf16(unsigned u) { return __uint_as_float(u & 0xffff0000u); }

__global__ __launch_bounds__(256) void zero_ws_kernel(float* __restrict__ ws, int n) {
    int i = blockIdx.x * blockDim.x + threadIdx.x;
    if (i < n) ws[i] = 0.0f;
}

// fp32 (NUM_NODE,DIM) -> packed bf16 table; also zero-inits the 64 KB
// (BZ,DIM) accumulator (first 16384 threads) to save a launch.
__global__ __launch_bounds__(256) void cvt_emb_zero_kernel(
    const float4* __restrict__ src, uint2* __restrict__ dst, int n4,
    float* __restrict__ ypre, int nacc) {
    int i = blockIdx.x * blockDim.x + threadIdx.x;
    if (i < n4) {
        float4 v = src[i];
        uint2 o;
        o.x = bf16_rne(v.x) | (bf16_rne(v.y) << 16);
        o.y = bf16_rne(v.z) | (bf16_rne(v.w) << 16);
        dst[i] = o;
    }
    if (i < nacc) ypre[i] = 0.0f;
}

// One wave per (b,s) position. A 16B/lane uint4 load covers TWO 512B bf16
// rows (lanes 0-31 -> neighbor 2j, lanes 32-63 -> neighbor 2j+1): whole
// neighborhood = 8 loads, issued back-to-back before consumption. Block
// result goes straight into the 64 KB (BZ,DIM) accumulator via atomicAdd
// (128 adds/address -> negligible contention), killing the partials
// round-trip. 8 waves/SIMD for HBM-latency hiding on the edge_w gathers.
__global__ __launch_bounds__(256, 8) void gnn_gather_kernel(
    const int*   __restrict__ X,        // (BZ, SEQ)
    const int*   __restrict__ NX,       // (BZ, SEQ, NBR)
    const int*   __restrict__ EW,       // (BZ, SEQ, NBR)
    const char*  __restrict__ embb,     // (NUM_NODE, ROWB) packed bf16 table
    const float* __restrict__ edge_w,   // (EDGE_ROWS, 1)
    const float* __restrict__ node_w,   // (NUM_NODE, 1)
    float*       __restrict__ ypre)     // (BZ, DIM) atomic accumulator
{
    __shared__ float lds[4][DIM];

    const int b     = blockIdx.x / NCHUNK2;
    const int chunk = blockIdx.x % NCHUNK2;
    const int wave  = threadIdx.x >> 6;
    const int lane  = threadIdx.x & 63;
    const int half  = lane >> 5;
    const int sub   = lane & 31;
    const int voff  = sub * 16;          // byte offset within a bf16 row

    const int s  = chunk * 4 + wave;
    const int bs = b * SEQ + s;

    // 16 lanes fetch this position's neighbor ids / edge-weight indices
    int   nxv = 0;
    float ewv = 0.f;
    if (lane < NBR) {
        nxv = __builtin_nontemporal_load(&NX[bs * NBR + lane]);
        const int ewi = __builtin_nontemporal_load(&EW[bs * NBR + lane]);
        ewv = __builtin_nontemporal_load(&edge_w[ewi]);
    }
    const int   x  = X[bs];        // wave-uniform address -> broadcast line
    const float nn = node_w[x];

    // ---- issue ALL gather loads back-to-back ----
    uint4 e[8];
    #pragma unroll
    for (int j = 0; j < 8; ++j) {
        const int n0 = bcast_i(nxv, 2 * j);
        const int n1 = bcast_i(nxv, 2 * j + 1);
        const int n  = half ? n1 : n0;
        e[j] = *(const uint4*)(embb + (size_t)n * ROWB + voff);
    }
    const uint4 es = *(const uint4*)(embb + (size_t)x * ROWB + voff); // self row

    // ---- consume in issue order (decreasing vmcnt) ----
    float m[8];
    #pragma unroll
    for (int i = 0; i < 8; ++i) m[i] = -INFINITY;

    #pragma unroll
    for (int j = 0; j < 8; ++j) {
        const float w0 = bcast_f(ewv, 2 * j);
        const float w1 = bcast_f(ewv, 2 * j + 1);
        const float w  = half ? w1 : w0;
        m[0] = fmaxf(m[0], lo_bf16(e[j].x) * w);
        m[1] = fmaxf(m[1], hi_bf16(e[j].x) * w);
        m[2] = fmaxf(m[2], lo_bf16(e[j].y) * w);
        m[3] = fmaxf(m[3], hi_bf16(e[j].y) * w);
        m[4] = fmaxf(m[4], lo_bf16(e[j].z) * w);
        m[5] = fmaxf(m[5], hi_bf16(e[j].z) * w);
        m[6] = fmaxf(m[6], lo_bf16(e[j].w) * w);
        m[7] = fmaxf(m[7], hi_bf16(e[j].w) * w);
    }

    // combine the two half-wave neighbor subsets
    #pragma unroll
    for (int i = 0; i < 8; ++i)
        m[i] = fmaxf(m[i], __shfl_xor(m[i], 32));

    const float om = 1.0f - nn;
    float acc[8];
    acc[0] = om * m[0] + nn * lo_bf16(es.x);
    acc[1] = om * m[1] + nn * hi_bf16(es.x);
    acc[2] = om * m[2] + nn * lo_bf16(es.y);
    acc[3] = om * m[3] + nn * hi_bf16(es.y);
    acc[4] = om * m[4] + nn * lo_bf16(es.z);
    acc[5] = om * m[5] + nn * hi_bf16(es.z);
    acc[6] = om * m[6] + nn * lo_bf16(es.w);
    acc[7] = om * m[7] + nn * hi_bf16(es.w);

    if (half == 0) {
        *(float4*)&lds[wave][8 * sub]     = make_float4(acc[0], acc[1], acc[2], acc[3]);
        *(float4*)&lds[wave][8 * sub + 4] = make_float4(acc[4], acc[5], acc[6], acc[7]);
    }
    __syncthreads();

    const int t = threadIdx.x;   // 0..255 -> one dim each
    atomicAdd(&ypre[b * DIM + t], lds[0][t] + lds[1][t] + lds[2][t] + lds[3][t]);
}

// Fallback (tiny ws): fp32 gathers, atomic accumulation into (BZ,DIM).
__global__ __launch_bounds__(256) void gnn_gather_f32_kernel(
    const int*   __restrict__ X,
    const int*   __restrict__ NX,
    const int*   __restrict__ EW,
    const float* __restrict__ node_emb,
    const float* __restrict__ edge_w,
    const float* __restrict__ node_w,
    float*       __restrict__ dst)      // (BZ, DIM) atomic
{
    __shared__ float lds[4][DIM];
    const int b     = blockIdx.x / NCHUNK16;
    const int chunk = blockIdx.x % NCHUNK16;
    const int wave  = threadIdx.x >> 6;
    const int lane  = threadIdx.x & 63;
    const int s0  = chunk * 16 + wave * 4;
    const int bs0 = b * SEQ + s0;

    const int   nx  = NX[bs0 * NBR + lane];
    const float ew  = edge_w[EW[bs0 * NBR + lane]];
    int xv = 0; float nwv = 0.f;
    if (lane < 4) { xv = X[bs0 + lane]; nwv = node_w[xv]; }

    float4 acc = make_float4(0.f, 0.f, 0.f, 0.f);
    for (int p = 0; p < 4; ++p) {
        float4 m = make_float4(-INFINITY, -INFINITY, -INFINITY, -INFINITY);
        for (int k = 0; k < NBR; ++k) {
            const int   n = bcast_i(nx, p * 16 + k);
            const float w = bcast_f(ew, p * 16 + k);
            const float4 e = *(const float4*)(node_emb + (size_t)n * DIM + 4 * lane);
            m.x = fmaxf(m.x, e.x * w); m.y = fmaxf(m.y, e.y * w);
            m.z = fmaxf(m.z, e.z * w); m.w = fmaxf(m.w, e.w * w);
        }
        const int   x  = bcast_i(xv, p);
        const float nn = bcast_f(nwv, p);
        const float om = 1.0f - nn;
        const float4 r = *(const float4*)(node_emb + (size_t)x * DIM + 4 * lane);
        acc.x += om * m.x + nn * r.x; acc.y += om * m.y + nn * r.y;
        acc.z += om * m.z + nn * r.z; acc.w += om * m.w + nn * r.w;
    }
    *(float4*)&lds[wave][4 * lane] = acc;
    __syncthreads();
    const int t = threadIdx.x;
    atomicAdd(&dst[b * DIM + t], lds[0][t] + lds[1][t] + lds[2][t] + lds[3][t]);
}

// One block (256 threads) per batch row: GEMV(256->20) + bias + relu +
// log_softmax from the 64 KB accumulator.
__global__ __launch_bounds__(256) void gnn_head_kernel(
    const float* __restrict__ ypre,  // (BZ, DIM)
    const float* __restrict__ fc_W,  // (NCLS, DIM)
    const float* __restrict__ fc_b,  // (NCLS,)
    float*       __restrict__ out)   // (BZ, NCLS)
{
    __shared__ float vals[NCLS];
    __shared__ float lse;

    const int b = blockIdx.x;
    const int t = threadIdx.x;
    const int wave = t >> 6;
    const int lane = t & 63;

    const float4 y4 = *(const float4*)(ypre + b * DIM + 4 * lane);

    #pragma unroll
    for (int ci = 0; ci < 5; ++ci) {
        const int c = wave * 5 + ci;           // 4 waves x 5 classes = 20
        const float4 w4 = *(const float4*)(fc_W + c * DIM + 4 * lane);
        float d = y4.x * w4.x + y4.y * w4.y + y4.z * w4.z + y4.w * w4.w;
        #pragma unroll
        for (int off = 32; off; off >>= 1) d += __shfl_xor(d, off);
        if (lane == 0) vals[c] = fmaxf(d + fc_b[c], 0.0f);
    }
    __syncthreads();

    if (t == 0) {
        float mx = -INFINITY;
        for (int c = 0; c < NCLS; ++c) mx = fmaxf(mx, vals[c]);
        float s = 0.0f;
        for (int c = 0; c < NCLS; ++c) s += expf(vals[c] - mx);
        lse = mx + logf(s);
    }
    __syncthreads();

    if (t < NCLS) out[b * NCLS + t] = vals[t] - lse;
}

extern "C" void kernel_launch(void* const* d_in, const int* in_sizes, int n_in,
                              void* d_out, int out_size, void* d_ws, size_t ws_size,
                              hipStream_t stream) {
    const int*   X        = (const int*)  d_in[0];
    const int*   NX       = (const int*)  d_in[1];
    const int*   EW       = (const int*)  d_in[2];
    const float* node_emb = (const float*)d_in[3];
    const float* edge_w   = (const float*)d_in[4];
    const float* node_w   = (const float*)d_in[5];
    const float* fc_W     = (const float*)d_in[6];
    const float* fc_b     = (const float*)d_in[7];
    float* out = (float*)d_out;

    const size_t acc_bytes = (size_t)BZ * DIM * sizeof(float);                 // 64 KB
    const size_t emb_bytes = (size_t)NUM_NODE * DIM * sizeof(unsigned short);  // 2.56 MB
    float* ypre = (float*)d_ws;
    char*  embb = (char*)d_ws + acc_bytes;

    if (ws_size >= acc_bytes + emb_bytes) {
        const int n4 = NUM_NODE * DIM / 4;   // 320000
        cvt_emb_zero_kernel<<<(n4 + 255) / 256, 256, 0, stream>>>(
            (const float4*)node_emb, (uint2*)embb, n4, ypre, BZ * DIM);
        gnn_gather_kernel<<<BZ * NCHUNK2, 256, 0, stream>>>(
            X, NX, EW, embb, edge_w, node_w, ypre);
        gnn_head_kernel<<<BZ, 256, 0, stream>>>(ypre, fc_W, fc_b, out);
    } else {
        zero_ws_kernel<<<(BZ * DIM + 255) / 256, 256, 0, stream>>>(ypre, BZ * DIM);
        gnn_gather_f32_kernel<<<BZ * NCHUNK16, 256, 0, stream>>>(
            X, NX, EW, node_emb, edge_w, node_w, ypre);
        gnn_head_kernel<<<BZ, 256, 0, stream>>>(ypre, fc_W, fc_b, out);
    }
}